// Round 17
// baseline (70.448 us; speedup 1.0000x reference)
//
#include <hip/hip_runtime.h>

#define N_NODES 40000
#define N_EDGES 160000
#define N_FEATS 74
#define DD 1024
#define HD 3072
#define N_GRAPHS 800

#define NVB 768               // v-blocks: 4 g's per block, 3072 total
#define NTB 57                // task blocks: 222 L/R dots + c0, 4 waves each
// kScanPool geometry
#define SNR 200               // blocks = dst ranges
#define SRNG 200              // dsts per range (= 4 graphs)
#define SNTHR 1024            // 16 waves per block

__device__ __forceinline__ float waveReduceSum(float v) {
    #pragma unroll
    for (int off = 32; off > 0; off >>= 1)
        v += __shfl_down(v, off, 64);
    return v;
}
__device__ __forceinline__ float lrelu02(float x) { return x > 0.f ? x : 0.2f * x; }

// ---- K1 kVFused: v + V-column scatter + L/R columns + c0, one launch ----
// blocks [0,NVB): wave w computes g=4b+w: v_g = W1[g,:]·W2, then scatters
//   v_g*W[f,g] into lw9 V-column (LDS-combined per block, then atomics),
//   bgvpar[b] = sum_w v_g*bias[g].
// blocks [NVB,NVB+NTB): wave-task t<222: f,h -> lw9 L/R; t==222 -> c0.
__global__ __launch_bounds__(256) void kVFused(
    const float* __restrict__ W1, const float* __restrict__ W2,
    const float* __restrict__ b1, const float* __restrict__ b2,
    const float* __restrict__ W, const float* __restrict__ al,
    const float* __restrict__ ar, const float* __restrict__ bias,
    float* __restrict__ c0, float* __restrict__ bgvpar,
    float* __restrict__ lw9) {
    int wave = threadIdx.x >> 6, lane = threadIdx.x & 63;
    if (blockIdx.x < NVB) {
        __shared__ float wvp[4][80];
        __shared__ float bp[4];
        int g = blockIdx.x * 4 + wave;
        const float4* row = (const float4*)(W1 + (size_t)g * DD);
        const float4* w2v = (const float4*)W2;
        float acc = 0.f;
        #pragma unroll
        for (int k = 0; k < 4; ++k) {
            float4 a = row[lane + 64 * k];
            float4 b = w2v[lane + 64 * k];
            acc += a.x * b.x + a.y * b.y + a.z * b.z + a.w * b.w;
        }
        acc = waveReduceSum(acc);
        float vg = __shfl(acc, 0, 64);
        // scatter: f = lane (0..63) and f = 64+lane (lane<10)
        wvp[wave][lane] = W[(size_t)lane * HD + g] * vg;
        if (lane < N_FEATS - 64)
            wvp[wave][64 + lane] = W[(size_t)(64 + lane) * HD + g] * vg;
        if (!lane) bp[wave] = vg * bias[g];
        __syncthreads();
        int tid = threadIdx.x;
        if (tid < N_FEATS) {
            float s = wvp[0][tid] + wvp[1][tid] + wvp[2][tid] + wvp[3][tid];
            int h = (blockIdx.x * 4) >> 10;      // same head for the 4 g's
            atomicAdd(&lw9[tid * 9 + 6 + h], s);
        } else if (tid == N_FEATS) {
            bgvpar[blockIdx.x] = bp[0] + bp[1] + bp[2] + bp[3];
        }
    } else {
        int t = (blockIdx.x - NVB) * 4 + wave;
        if (t < N_FEATS * 3) {
            int f = t / 3, h = t - f * 3;
            const float4* rw = (const float4*)(W + (size_t)f * HD + h * DD);
            const float4* pl = (const float4*)(al + h * DD);
            const float4* pr = (const float4*)(ar + h * DD);
            float aL = 0.f, aR = 0.f;
            #pragma unroll
            for (int k = 0; k < 4; ++k) {
                float4 x = rw[lane + 64 * k];
                float4 l4 = pl[lane + 64 * k];
                float4 r4 = pr[lane + 64 * k];
                aL += x.x * l4.x + x.y * l4.y + x.z * l4.z + x.w * l4.w;
                aR += x.x * r4.x + x.y * r4.y + x.z * r4.z + x.w * r4.w;
            }
            aL = waveReduceSum(aL); aR = waveReduceSum(aR);
            if (!lane) { lw9[f * 9 + h] = aL; lw9[f * 9 + 3 + h] = aR; }
        } else if (t == N_FEATS * 3) {
            const float4* pb1 = (const float4*)b1;
            const float4* w2v = (const float4*)W2;
            float acc = 0.f;
            #pragma unroll
            for (int k = 0; k < 4; ++k) {
                float4 a = pb1[lane + 64 * k];
                float4 b = w2v[lane + 64 * k];
                acc += a.x * b.x + a.y * b.y + a.z * b.z + a.w * b.w;
            }
            acc = waveReduceSum(acc);
            if (!lane) c0[0] = acc + b2[0];
        }
    }
}

// ---- K2 kNode: 2 threads per node (f-range split); lw9 loaded directly ----
__global__ __launch_bounds__(256) void kNode(const float* __restrict__ feats,
                      const float* __restrict__ lw9,
                      float4* __restrict__ sn4, float4* __restrict__ er4) {
    __shared__ float lw[N_FEATS * 9];
    int t = threadIdx.x;
    for (int i = t; i < N_FEATS * 9; i += 256) lw[i] = lw9[i];
    __syncthreads();
    int node = blockIdx.x * 128 + (t >> 1);
    if (node >= N_NODES) return;
    int half = t & 1;
    const float* row = feats + (size_t)node * N_FEATS;
    float a0=0,a1=0,a2=0,a3=0,a4=0,a5=0,a6=0,a7=0,a8=0;
    if (half == 0) {
        #pragma unroll
        for (int k = 0; k < 18; ++k) {
            float2 x2 = *(const float2*)(row + k * 2);
            const float* w0 = lw + (k * 2) * 9;
            a0 += x2.x*w0[0]; a1 += x2.x*w0[1]; a2 += x2.x*w0[2];
            a3 += x2.x*w0[3]; a4 += x2.x*w0[4]; a5 += x2.x*w0[5];
            a6 += x2.x*w0[6]; a7 += x2.x*w0[7]; a8 += x2.x*w0[8];
            const float* w1 = w0 + 9;
            a0 += x2.y*w1[0]; a1 += x2.y*w1[1]; a2 += x2.y*w1[2];
            a3 += x2.y*w1[3]; a4 += x2.y*w1[4]; a5 += x2.y*w1[5];
            a6 += x2.y*w1[6]; a7 += x2.y*w1[7]; a8 += x2.y*w1[8];
        }
        float x = row[36];
        const float* wp = lw + 36 * 9;
        a0 += x*wp[0]; a1 += x*wp[1]; a2 += x*wp[2];
        a3 += x*wp[3]; a4 += x*wp[4]; a5 += x*wp[5];
        a6 += x*wp[6]; a7 += x*wp[7]; a8 += x*wp[8];
    } else {
        float x = row[37];
        const float* wp = lw + 37 * 9;
        a0 += x*wp[0]; a1 += x*wp[1]; a2 += x*wp[2];
        a3 += x*wp[3]; a4 += x*wp[4]; a5 += x*wp[5];
        a6 += x*wp[6]; a7 += x*wp[7]; a8 += x*wp[8];
        #pragma unroll
        for (int k = 0; k < 18; ++k) {
            float2 x2 = *(const float2*)(row + 38 + k * 2);
            const float* w0 = lw + (38 + k * 2) * 9;
            a0 += x2.x*w0[0]; a1 += x2.x*w0[1]; a2 += x2.x*w0[2];
            a3 += x2.x*w0[3]; a4 += x2.x*w0[4]; a5 += x2.x*w0[5];
            a6 += x2.x*w0[6]; a7 += x2.x*w0[7]; a8 += x2.x*w0[8];
            const float* w1 = w0 + 9;
            a0 += x2.y*w1[0]; a1 += x2.y*w1[1]; a2 += x2.y*w1[2];
            a3 += x2.y*w1[3]; a4 += x2.y*w1[4]; a5 += x2.y*w1[5];
            a6 += x2.y*w1[6]; a7 += x2.y*w1[7]; a8 += x2.y*w1[8];
        }
    }
    a0 += __shfl_xor(a0, 1, 64); a1 += __shfl_xor(a1, 1, 64);
    a2 += __shfl_xor(a2, 1, 64); a3 += __shfl_xor(a3, 1, 64);
    a4 += __shfl_xor(a4, 1, 64); a5 += __shfl_xor(a5, 1, 64);
    a6 += __shfl_xor(a6, 1, 64); a7 += __shfl_xor(a7, 1, 64);
    a8 += __shfl_xor(a8, 1, 64);
    if (!half) {
        sn4[node * 2]     = make_float4(a0, a1, a2, 0.f);  // el
        sn4[node * 2 + 1] = make_float4(a6, a7, a8, 0.f);  // hv
        er4[node]         = make_float4(a3, a4, a5, 0.f);
    }
}

// dense batch edge processing from a wave's circular queue
__device__ __forceinline__ void processBatch(const int* myq, int wtail, int lane, int nact,
        const int* __restrict__ src, const float4* __restrict__ sn4,
        const float4* __restrict__ er4, int rbase, float* acc) {
    if (lane < nact) {
        int pk = myq[(wtail + lane) & 127];
        int rr = pk & 255;
        int e  = ((unsigned)pk) >> 8;
        int s  = src[e];
        float4 L = sn4[s * 2];
        float4 V = sn4[s * 2 + 1];
        float4 R = er4[rbase + rr];
        float e0 = expf(lrelu02(L.x + R.x));
        float e1 = expf(lrelu02(L.y + R.y));
        float e2 = expf(lrelu02(L.z + R.z));
        float* p = acc + rr * 6;
        atomicAdd(p + 0, e0 * V.x);
        atomicAdd(p + 1, e1 * V.y);
        atomicAdd(p + 2, e2 * V.z);
        atomicAdd(p + 3, e0);
        atomicAdd(p + 4, e1);
        atomicAdd(p + 5, e2);
    }
}

// ---- K3 kScanPool: 16-wave barrier-free scan + fused graph pooling ----
__global__ __launch_bounds__(SNTHR) void kScanPool(const int* __restrict__ src,
        const int* __restrict__ dst, const float4* __restrict__ sn4,
        const float4* __restrict__ er4, const float* __restrict__ bgvpar,
        const float* __restrict__ c0, float* __restrict__ y) {
    __shared__ float acc[SRNG * 6];     // 4.8 KB
    __shared__ int wq[16][128];         // per-wave circular queues, 8 KB
    int tid = threadIdx.x, wave = tid >> 6, lane = tid & 63;
    for (int i = tid; i < SRNG * 6; i += SNTHR) acc[i] = 0.f;
    __syncthreads();
    const int rbase = blockIdx.x * SRNG;
    int* myq = wq[wave];
    int wcnt = 0, wtail = 0;
    const int SPAN4 = (N_EDGES / 4) / 16;          // 2500
    const int NITER = (SPAN4 + 63) / 64;           // 40 uniform rounds
    const int4* d4 = (const int4*)dst;
    int i0 = wave * SPAN4;
    for (int it = 0; it < NITER; ++it) {
        int j = it * 64 + lane;
        bool valid = j < SPAN4;
        int i = i0 + (valid ? j : 0);
        int4 d = d4[i];
        #pragma unroll
        for (int k = 0; k < 4; ++k) {
            int dd = (k == 0) ? d.x : (k == 1) ? d.y : (k == 2) ? d.z : d.w;
            unsigned rr = (unsigned)(dd - rbase);
            bool match = valid && (rr < SRNG);
            unsigned long long m = __ballot(match);
            if (m) {
                if (match) {
                    int off = __popcll(m & ((1ULL << lane) - 1ULL));
                    myq[(wcnt + off) & 127] = ((i * 4 + k) << 8) | (int)rr;
                }
                wcnt += (int)__popcll(m);
                if (wcnt - wtail >= 64) {
                    processBatch(myq, wtail, lane, 64, src, sn4, er4, rbase, acc);
                    wtail += 64;
                }
            }
        }
    }
    int rem = wcnt - wtail;
    if (rem > 0) processBatch(myq, wtail, lane, rem, src, sn4, er4, rbase, acc);
    __syncthreads();
    if (wave < 4) {
        float b = 0.f;
        for (int i = lane; i < NVB; i += 64) b += bgvpar[i];
        b = waveReduceSum(b);
        float cacc = 0.f;
        if (lane < 50) {
            const float* p = acc + (wave * 50 + lane) * 6;
            if (p[3] > 0.f) cacc = p[0] / p[3] + p[1] / p[4] + p[2] / p[5];
        }
        cacc = waveReduceSum(cacc);
        if (!lane) y[blockIdx.x * 4 + wave] = cacc * (1.f / 50.f) + b + c0[0];
    }
}

extern "C" void kernel_launch(void* const* d_in, const int* in_sizes, int n_in,
                              void* d_out, int out_size, void* d_ws, size_t ws_size,
                              hipStream_t stream) {
    const float* feats = (const float*)d_in[0];
    const float* W     = (const float*)d_in[1];
    const float* al    = (const float*)d_in[2];
    const float* ar    = (const float*)d_in[3];
    const float* bias  = (const float*)d_in[4];
    const float* W1    = (const float*)d_in[5];
    const float* b1    = (const float*)d_in[6];
    const float* W2    = (const float*)d_in[7];
    const float* b2    = (const float*)d_in[8];
    const int*   src   = (const int*)d_in[9];
    const int*   dst   = (const int*)d_in[10];

    float* ws     = (float*)d_ws;
    float* lw9    = ws;                    // 666 (pad 672)
    float* c0     = ws + 672;              // 1
    float* bgvpar = ws + 704;              // 768
    float* sn     = ws + 2048;             // N*8 (16B aligned)
    float* er     = sn + N_NODES * 8;      // N*4
    float* y      = (float*)d_out;

    // zero lw9 (V-column is atomically accumulated; L/R overwritten anyway)
    hipMemsetAsync(lw9, 0, 672 * sizeof(float), stream);
    hipLaunchKernelGGL(kVFused, dim3(NVB + NTB), dim3(256), 0, stream,
                       W1, W2, b1, b2, W, al, ar, bias, c0, bgvpar, lw9);
    hipLaunchKernelGGL(kNode, dim3((N_NODES + 127) / 128), dim3(256), 0, stream,
                       feats, lw9, (float4*)sn, (float4*)er);
    hipLaunchKernelGGL(kScanPool, dim3(SNR), dim3(SNTHR), 0, stream,
                       src, dst, (const float4*)sn, (const float4*)er, bgvpar, c0, y);
}

// Round 18
// 52.918 us; speedup vs baseline: 1.3313x; 1.3313x over previous
//
#include <hip/hip_runtime.h>

#define N_NODES 40000
#define N_EDGES 160000
#define N_FEATS 74
#define DD 1024
#define HD 3072
#define N_GRAPHS 800

#define NVB 192               // v-blocks: 16 g's per block
#define NTB 57                // task blocks: 222 L/R dots + c0, 4 waves each
// kScanPool geometry
#define SNR 200               // blocks = dst ranges
#define SRNG 200              // dsts per range (= 4 graphs)
#define SNTHR 1024            // 16 waves per block

__device__ __forceinline__ float waveReduceSum(float v) {
    #pragma unroll
    for (int off = 32; off > 0; off >>= 1)
        v += __shfl_down(v, off, 64);
    return v;
}
__device__ __forceinline__ float lrelu02(float x) { return x > 0.f ? x : 0.2f * x; }

// ---- K1 kVFused: single launch, deterministic writes only ----
// blocks [0,NVB): block b owns g in [b*16,b*16+16) (head h=b>>6):
//   vs[j] = W1[g,:]·W2 ; wvpar[b*80+f] = sum_j W[f,g0+j]*vs[j] ; bgvpar[b]
// blocks [NVB,..): wave-task t<222 -> lw6[f*6+{h,3+h}] ; t==222 -> c0
__global__ __launch_bounds__(256) void kVFused(
    const float* __restrict__ W1, const float* __restrict__ W2,
    const float* __restrict__ b1, const float* __restrict__ b2,
    const float* __restrict__ W, const float* __restrict__ al,
    const float* __restrict__ ar, const float* __restrict__ bias,
    float* __restrict__ c0, float* __restrict__ bgvpar,
    float* __restrict__ wvpar, float* __restrict__ lw6) {
    int wave = threadIdx.x >> 6, lane = threadIdx.x & 63;
    if (blockIdx.x < NVB) {
        __shared__ float vs[16];
        int b = blockIdx.x;
        int g0 = b * 16;
        const float4* w2v = (const float4*)W2;
        #pragma unroll
        for (int q = 0; q < 4; ++q) {
            int g = g0 + wave * 4 + q;
            const float4* row = (const float4*)(W1 + (size_t)g * DD);
            float acc = 0.f;
            #pragma unroll
            for (int k = 0; k < 4; ++k) {
                float4 a = row[lane + 64 * k];
                float4 bb = w2v[lane + 64 * k];
                acc += a.x * bb.x + a.y * bb.y + a.z * bb.z + a.w * bb.w;
            }
            acc = waveReduceSum(acc);
            if (!lane) vs[wave * 4 + q] = acc;
        }
        __syncthreads();
        int tid = threadIdx.x;
        if (tid < N_FEATS) {
            const float4* wr = (const float4*)(W + (size_t)tid * HD + g0);
            const float4* vv = (const float4*)vs;
            float s = 0.f;
            #pragma unroll
            for (int k = 0; k < 4; ++k) {
                float4 a = wr[k];
                float4 bb = vv[k];
                s += a.x * bb.x + a.y * bb.y + a.z * bb.z + a.w * bb.w;
            }
            wvpar[b * 80 + tid] = s;
        } else if (tid == N_FEATS) {
            float s = 0.f;
            #pragma unroll
            for (int j = 0; j < 16; ++j) s += vs[j] * bias[g0 + j];
            bgvpar[b] = s;
        }
    } else {
        int t = (blockIdx.x - NVB) * 4 + wave;
        if (t < N_FEATS * 3) {
            int f = t / 3, h = t - f * 3;
            const float4* rw = (const float4*)(W + (size_t)f * HD + h * DD);
            const float4* pl = (const float4*)(al + h * DD);
            const float4* pr = (const float4*)(ar + h * DD);
            float aL = 0.f, aR = 0.f;
            #pragma unroll
            for (int k = 0; k < 4; ++k) {
                float4 x = rw[lane + 64 * k];
                float4 l4 = pl[lane + 64 * k];
                float4 r4 = pr[lane + 64 * k];
                aL += x.x * l4.x + x.y * l4.y + x.z * l4.z + x.w * l4.w;
                aR += x.x * r4.x + x.y * r4.y + x.z * r4.z + x.w * r4.w;
            }
            aL = waveReduceSum(aL); aR = waveReduceSum(aR);
            if (!lane) { lw6[f * 6 + h] = aL; lw6[f * 6 + 3 + h] = aR; }
        } else if (t == N_FEATS * 3) {
            const float4* pb1 = (const float4*)b1;
            const float4* w2v = (const float4*)W2;
            float acc = 0.f;
            #pragma unroll
            for (int k = 0; k < 4; ++k) {
                float4 a = pb1[lane + 64 * k];
                float4 bb = w2v[lane + 64 * k];
                acc += a.x * bb.x + a.y * bb.y + a.z * bb.z + a.w * bb.w;
            }
            acc = waveReduceSum(acc);
            if (!lane) c0[0] = acc + b2[0];
        }
    }
}

// ---- K2 kNode: builds lw table (L/R from lw6, V summed from wvpar) ----
__global__ __launch_bounds__(256) void kNode(const float* __restrict__ feats,
                      const float* __restrict__ lw6, const float* __restrict__ wvpar,
                      float4* __restrict__ sn4, float4* __restrict__ er4) {
    __shared__ float lw[N_FEATS * 9];
    int t = threadIdx.x;
    for (int i = t; i < N_FEATS * 6; i += 256)
        lw[(i / 6) * 9 + (i % 6)] = lw6[i];
    for (int j = t; j < N_FEATS * 3; j += 256) {   // j = f*3+h
        int f = j / 3, h = j - f * 3;
        float s = 0.f;
        #pragma unroll 8
        for (int b = 0; b < 64; ++b)
            s += wvpar[(h * 64 + b) * 80 + f];
        lw[f * 9 + 6 + h] = s;
    }
    __syncthreads();
    int node = blockIdx.x * 128 + (t >> 1);
    if (node >= N_NODES) return;
    int half = t & 1;
    const float* row = feats + (size_t)node * N_FEATS;
    float a0=0,a1=0,a2=0,a3=0,a4=0,a5=0,a6=0,a7=0,a8=0;
    if (half == 0) {
        #pragma unroll
        for (int k = 0; k < 18; ++k) {
            float2 x2 = *(const float2*)(row + k * 2);
            const float* w0 = lw + (k * 2) * 9;
            a0 += x2.x*w0[0]; a1 += x2.x*w0[1]; a2 += x2.x*w0[2];
            a3 += x2.x*w0[3]; a4 += x2.x*w0[4]; a5 += x2.x*w0[5];
            a6 += x2.x*w0[6]; a7 += x2.x*w0[7]; a8 += x2.x*w0[8];
            const float* w1 = w0 + 9;
            a0 += x2.y*w1[0]; a1 += x2.y*w1[1]; a2 += x2.y*w1[2];
            a3 += x2.y*w1[3]; a4 += x2.y*w1[4]; a5 += x2.y*w1[5];
            a6 += x2.y*w1[6]; a7 += x2.y*w1[7]; a8 += x2.y*w1[8];
        }
        float x = row[36];
        const float* wp = lw + 36 * 9;
        a0 += x*wp[0]; a1 += x*wp[1]; a2 += x*wp[2];
        a3 += x*wp[3]; a4 += x*wp[4]; a5 += x*wp[5];
        a6 += x*wp[6]; a7 += x*wp[7]; a8 += x*wp[8];
    } else {
        float x = row[37];
        const float* wp = lw + 37 * 9;
        a0 += x*wp[0]; a1 += x*wp[1]; a2 += x*wp[2];
        a3 += x*wp[3]; a4 += x*wp[4]; a5 += x*wp[5];
        a6 += x*wp[6]; a7 += x*wp[7]; a8 += x*wp[8];
        #pragma unroll
        for (int k = 0; k < 18; ++k) {
            float2 x2 = *(const float2*)(row + 38 + k * 2);
            const float* w0 = lw + (38 + k * 2) * 9;
            a0 += x2.x*w0[0]; a1 += x2.x*w0[1]; a2 += x2.x*w0[2];
            a3 += x2.x*w0[3]; a4 += x2.x*w0[4]; a5 += x2.x*w0[5];
            a6 += x2.x*w0[6]; a7 += x2.x*w0[7]; a8 += x2.x*w0[8];
            const float* w1 = w0 + 9;
            a0 += x2.y*w1[0]; a1 += x2.y*w1[1]; a2 += x2.y*w1[2];
            a3 += x2.y*w1[3]; a4 += x2.y*w1[4]; a5 += x2.y*w1[5];
            a6 += x2.y*w1[6]; a7 += x2.y*w1[7]; a8 += x2.y*w1[8];
        }
    }
    a0 += __shfl_xor(a0, 1, 64); a1 += __shfl_xor(a1, 1, 64);
    a2 += __shfl_xor(a2, 1, 64); a3 += __shfl_xor(a3, 1, 64);
    a4 += __shfl_xor(a4, 1, 64); a5 += __shfl_xor(a5, 1, 64);
    a6 += __shfl_xor(a6, 1, 64); a7 += __shfl_xor(a7, 1, 64);
    a8 += __shfl_xor(a8, 1, 64);
    if (!half) {
        sn4[node * 2]     = make_float4(a0, a1, a2, 0.f);  // el
        sn4[node * 2 + 1] = make_float4(a6, a7, a8, 0.f);  // hv
        er4[node]         = make_float4(a3, a4, a5, 0.f);
    }
}

// dense batch edge processing from a wave's circular queue
__device__ __forceinline__ void processBatch(const int* myq, int wtail, int lane, int nact,
        const int* __restrict__ src, const float4* __restrict__ sn4,
        const float4* __restrict__ er4, int rbase, float* acc) {
    if (lane < nact) {
        int pk = myq[(wtail + lane) & 127];
        int rr = pk & 255;
        int e  = ((unsigned)pk) >> 8;
        int s  = src[e];
        float4 L = sn4[s * 2];
        float4 V = sn4[s * 2 + 1];
        float4 R = er4[rbase + rr];
        float e0 = expf(lrelu02(L.x + R.x));
        float e1 = expf(lrelu02(L.y + R.y));
        float e2 = expf(lrelu02(L.z + R.z));
        float* p = acc + rr * 6;
        atomicAdd(p + 0, e0 * V.x);
        atomicAdd(p + 1, e1 * V.y);
        atomicAdd(p + 2, e2 * V.z);
        atomicAdd(p + 3, e0);
        atomicAdd(p + 4, e1);
        atomicAdd(p + 5, e2);
    }
}

// ---- K3 kScanPool: 16-wave barrier-free scan + fused graph pooling ----
__global__ __launch_bounds__(SNTHR) void kScanPool(const int* __restrict__ src,
        const int* __restrict__ dst, const float4* __restrict__ sn4,
        const float4* __restrict__ er4, const float* __restrict__ bgvpar,
        const float* __restrict__ c0, float* __restrict__ y) {
    __shared__ float acc[SRNG * 6];     // 4.8 KB
    __shared__ int wq[16][128];         // per-wave circular queues, 8 KB
    int tid = threadIdx.x, wave = tid >> 6, lane = tid & 63;
    for (int i = tid; i < SRNG * 6; i += SNTHR) acc[i] = 0.f;
    __syncthreads();
    const int rbase = blockIdx.x * SRNG;
    int* myq = wq[wave];
    int wcnt = 0, wtail = 0;
    const int SPAN4 = (N_EDGES / 4) / 16;          // 2500
    const int NITER = (SPAN4 + 63) / 64;           // 40 uniform rounds
    const int4* d4 = (const int4*)dst;
    int i0 = wave * SPAN4;
    for (int it = 0; it < NITER; ++it) {
        int j = it * 64 + lane;
        bool valid = j < SPAN4;
        int i = i0 + (valid ? j : 0);
        int4 d = d4[i];
        #pragma unroll
        for (int k = 0; k < 4; ++k) {
            int dd = (k == 0) ? d.x : (k == 1) ? d.y : (k == 2) ? d.z : d.w;
            unsigned rr = (unsigned)(dd - rbase);
            bool match = valid && (rr < SRNG);
            unsigned long long m = __ballot(match);
            if (m) {
                if (match) {
                    int off = __popcll(m & ((1ULL << lane) - 1ULL));
                    myq[(wcnt + off) & 127] = ((i * 4 + k) << 8) | (int)rr;
                }
                wcnt += (int)__popcll(m);
                if (wcnt - wtail >= 64) {
                    processBatch(myq, wtail, lane, 64, src, sn4, er4, rbase, acc);
                    wtail += 64;
                }
            }
        }
    }
    int rem = wcnt - wtail;
    if (rem > 0) processBatch(myq, wtail, lane, rem, src, sn4, er4, rbase, acc);
    __syncthreads();
    if (wave < 4) {
        float b = 0.f;
        for (int i = lane; i < NVB; i += 64) b += bgvpar[i];
        b = waveReduceSum(b);
        float cacc = 0.f;
        if (lane < 50) {
            const float* p = acc + (wave * 50 + lane) * 6;
            if (p[3] > 0.f) cacc = p[0] / p[3] + p[1] / p[4] + p[2] / p[5];
        }
        cacc = waveReduceSum(cacc);
        if (!lane) y[blockIdx.x * 4 + wave] = cacc * (1.f / 50.f) + b + c0[0];
    }
}

extern "C" void kernel_launch(void* const* d_in, const int* in_sizes, int n_in,
                              void* d_out, int out_size, void* d_ws, size_t ws_size,
                              hipStream_t stream) {
    const float* feats = (const float*)d_in[0];
    const float* W     = (const float*)d_in[1];
    const float* al    = (const float*)d_in[2];
    const float* ar    = (const float*)d_in[3];
    const float* bias  = (const float*)d_in[4];
    const float* W1    = (const float*)d_in[5];
    const float* b1    = (const float*)d_in[6];
    const float* W2    = (const float*)d_in[7];
    const float* b2    = (const float*)d_in[8];
    const int*   src   = (const int*)d_in[9];
    const int*   dst   = (const int*)d_in[10];

    float* ws     = (float*)d_ws;
    float* lw6    = ws;                    // 444 (pad 448)
    float* c0     = ws + 448;              // 1
    float* bgvpar = ws + 512;              // 192
    float* wvpar  = ws + 1024;             // 192*80 = 15360
    float* sn     = ws + 16384;            // N*8 (16B aligned)
    float* er     = sn + N_NODES * 8;      // N*4
    float* y      = (float*)d_out;

    hipLaunchKernelGGL(kVFused, dim3(NVB + NTB), dim3(256), 0, stream,
                       W1, W2, b1, b2, W, al, ar, bias, c0, bgvpar, wvpar, lw6);
    hipLaunchKernelGGL(kNode, dim3((N_NODES + 127) / 128), dim3(256), 0, stream,
                       feats, lw6, wvpar, (float4*)sn, (float4*)er);
    hipLaunchKernelGGL(kScanPool, dim3(SNR), dim3(SNTHR), 0, stream,
                       src, dst, (const float4*)sn, (const float4*)er, bgvpar, c0, y);
}